// Round 6
// baseline (57745.923 us; speedup 1.0000x reference)
//
#include <hip/hip_runtime.h>
#include <stdint.h>

typedef unsigned short u16;
typedef _Float16 h2f16 __attribute__((ext_vector_type(2)));

#define BB    16
#define TENC  256
#define TDEC  200
#define NMELS 80
#define EDIM  512
#define PREN  256
#define ARN   1024
#define ATTN  128
#define NFILT 32
#define KSIZE 31

#define NBLK  256
#define NTHR  1024

// ---- ws layout (f32 slots) ----
#define OFF_X1H   0        // u32[22528]  packed fp16 pairs: rows [pre256|ctx512|ahA1024|ahB1024]
#define OFF_X2H   22528    // u32[28672]  rows [ah1024|ctx512|dhA1024|dhB1024]
#define OFF_AHF   51200    // f[16384]    ah f32 [u*16+b]
#define OFF_CTXF  67584    // f[2*8192]   ctx f32 ping-pong [pp][e*16+b]
#define OFF_DHF   83968    // f[16384]    dh f32
#define OFF_BAR   100352   // u32[2048]   hierarchical barrier
#define STATE_F   102400
#define OFF_PRETU 102400   // u32[409600] pre fp16-pairs [t][(j>>1)*16+b]
#define OFF_PMU   512000   // u16[524288] pm bf16 [b][j][tt]
#define OFF_X1U   774144   // u16[819200] prenet1 temp (pre-loop only)

__host__ __device__ inline void tf2x32(uint32_t k0, uint32_t k1, uint32_t x0, uint32_t x1,
                                       uint32_t &y0, uint32_t &y1) {
  uint32_t ks2 = k0 ^ k1 ^ 0x1BD11BDAu;
  x0 += k0; x1 += k1;
  const int R0[4] = {13, 15, 26, 6};
  const int R1[4] = {17, 29, 16, 24};
#pragma unroll
  for (int g = 0; g < 5; ++g) {
    const int *R = (g & 1) ? R1 : R0;
#pragma unroll
    for (int i = 0; i < 4; ++i) {
      x0 += x1;
      x1 = (x1 << R[i]) | (x1 >> (32 - R[i]));
      x1 ^= x0;
    }
    switch (g) {
      case 0: x0 += k1;  x1 += ks2 + 1u; break;
      case 1: x0 += ks2; x1 += k0 + 2u;  break;
      case 2: x0 += k0;  x1 += k1 + 3u;  break;
      case 3: x0 += k1;  x1 += ks2 + 4u; break;
      case 4: x0 += ks2; x1 += k0 + 5u;  break;
    }
  }
  y0 = x0; y1 = x1;
}

__device__ inline bool keep_mask(uint32_t k0, uint32_t k1, uint32_t idx) {
  uint32_t y0, y1;
  tf2x32(k0, k1, 0u, idx, y0, y1);
  return (((y0 ^ y1) >> 31) == 0u);
}

__device__ inline float bf2f(u16 v) {
  union { uint32_t u; float f; } x;
  x.u = ((uint32_t)v) << 16;
  return x.f;
}
__device__ inline u16 f2bf(float f) {
  union { float f; uint32_t u; } x;
  x.f = f;
  uint32_t r = ((x.u >> 16) & 1u) + 0x7FFFu;
  return (u16)((x.u + r) >> 16);
}
__device__ inline float sigm(float x) { return 1.f / (1.f + __expf(-x)); }
__device__ inline float ftanh(float x) {
  x = fminf(fmaxf(x, -15.f), 15.f);
  float e = __expf(2.f * x);
  return (e - 1.f) / (e + 1.f);
}

__device__ inline uint32_t packh2(float a, float b) {
  h2f16 h; h[0] = (_Float16)a; h[1] = (_Float16)b;
  union { h2f16 h; uint32_t u; } x; x.h = h; return x.u;
}
__device__ inline h2f16 u2h2(uint32_t u) {
  union { uint32_t u; h2f16 h; } x; x.u = u; return x.h;
}
__device__ inline float fdot2(h2f16 a, h2f16 b, float c) {
#if __has_builtin(__builtin_amdgcn_fdot2)
  return __builtin_amdgcn_fdot2(a, b, c, false);
#else
  return (float)a[0] * (float)b[0] + (float)a[1] * (float)b[1] + c;
#endif
}

// ---- coherent (LLC) access, agent scope, relaxed (zero cache maintenance) ----
__device__ inline float cload(const float *p) {
  uint32_t u = __hip_atomic_load((const uint32_t *)p, __ATOMIC_RELAXED,
                                 __HIP_MEMORY_SCOPE_AGENT);
  union { uint32_t u; float f; } x; x.u = u; return x.f;
}
__device__ inline void cstore(float *p, float v) {
  union { float f; uint32_t u; } x; x.f = v;
  __hip_atomic_store((uint32_t *)p, x.u, __ATOMIC_RELAXED,
                     __HIP_MEMORY_SCOPE_AGENT);
}
__device__ inline uint32_t cload_u32(const uint32_t *p) {
  return __hip_atomic_load(p, __ATOMIC_RELAXED, __HIP_MEMORY_SCOPE_AGENT);
}
__device__ inline void cstore_u32(uint32_t *p, uint32_t v) {
  __hip_atomic_store(p, v, __ATOMIC_RELAXED, __HIP_MEMORY_SCOPE_AGENT);
}

// ---- fence-free hierarchical epoch barrier ----
__device__ inline void gsync(unsigned int *bar, unsigned int e, int cb) {
  __syncthreads();
  if (threadIdx.x == 0) {
    asm volatile("s_waitcnt vmcnt(0)" ::: "memory");
    int g = cb & 7;
    unsigned int *arr = bar + g * 64;
    unsigned int *gct = bar + 512;
    unsigned int *rel = bar + 576 + g * 64;
    unsigned int old = __hip_atomic_fetch_add(arr, 1u, __ATOMIC_RELAXED,
                                              __HIP_MEMORY_SCOPE_AGENT);
    if (old == e * 32u - 1u) {
      unsigned int o2 = __hip_atomic_fetch_add(gct, 1u, __ATOMIC_RELAXED,
                                               __HIP_MEMORY_SCOPE_AGENT);
      if (o2 == e * 8u - 1u) {
#pragma unroll
        for (int g2 = 0; g2 < 8; ++g2)
          __hip_atomic_store(bar + 576 + g2 * 64, e, __ATOMIC_RELAXED,
                             __HIP_MEMORY_SCOPE_AGENT);
      }
    }
    while (__hip_atomic_load(rel, __ATOMIC_RELAXED, __HIP_MEMORY_SCOPE_AGENT) < e)
      __builtin_amdgcn_s_sleep(1);
  }
  __syncthreads();
}

// ---------------- setup kernels ----------------
__global__ __launch_bounds__(256) void k_prenet1(const float *__restrict__ dec_in,
                                                 const float *__restrict__ W1,
                                                 u16 *__restrict__ x1,
                                                 uint32_t k0, uint32_t k1) {
  int bid = blockIdx.x;
  int t = bid >> 4, b = bid & 15;
  int tid = threadIdx.x;
  __shared__ float di[NMELS];
  if (tid < NMELS)
    di[tid] = (t == 0) ? 0.f : dec_in[((size_t)b * NMELS + tid) * TDEC + (t - 1)];
  __syncthreads();
  int j = tid;
  float acc = 0.f;
#pragma unroll 4
  for (int m = 0; m < NMELS; ++m) acc += di[m] * W1[(size_t)m * PREN + j];
  acc = fmaxf(acc, 0.f);
  uint32_t idx = ((uint32_t)(t * BB + b)) * PREN + (uint32_t)j;
  acc = keep_mask(k0, k1, idx) ? acc * 2.f : 0.f;
  x1[(t * BB + b) * PREN + j] = f2bf(acc);
}

__global__ __launch_bounds__(256) void k_prenet2(const u16 *__restrict__ x1,
                                                 const float *__restrict__ W2,
                                                 uint32_t *__restrict__ preTuP,
                                                 uint32_t *__restrict__ x1hPre,
                                                 uint32_t k0, uint32_t k1) {
  int bid = blockIdx.x;
  int t = bid >> 4, b = bid & 15;
  int tid = threadIdx.x;
  __shared__ float xl[PREN];
  xl[tid] = bf2f(x1[(t * BB + b) * PREN + tid]);
  __syncthreads();
  int j = tid;
  float acc = 0.f;
#pragma unroll 4
  for (int k = 0; k < PREN; ++k) acc += xl[k] * W2[(size_t)k * PREN + j];
  acc = fmaxf(acc, 0.f);
  uint32_t idx = ((uint32_t)(t * BB + b)) * PREN + (uint32_t)j;
  acc = keep_mask(k0, k1, idx) ? acc * 2.f : 0.f;
  float accN = __shfl_down(acc, 1);
  if (!(j & 1)) {
    uint32_t pk = packh2(acc, accN);
    preTuP[(size_t)t * 2048 + (j >> 1) * 16 + b] = pk;
    if (t == 0) x1hPre[(j >> 1) * 16 + b] = pk;
  }
}

__global__ __launch_bounds__(256) void k_pm(const float *__restrict__ memory,
                                            const float *__restrict__ Wmem,
                                            u16 *__restrict__ pmu) {
  int p = blockIdx.x;
  int b = p & 15, jt = p >> 4;
  int tt = threadIdx.x;
  float acc[32];
#pragma unroll
  for (int j = 0; j < 32; ++j) acc[j] = 0.f;
  const float *mrow = memory + ((size_t)b * TENC + tt) * EDIM;
  const float *wb = Wmem + jt * 32;
  for (int e = 0; e < EDIM; ++e) {
    float mv = mrow[e];
    const float *wr = wb + (size_t)e * ATTN;
#pragma unroll
    for (int j = 0; j < 32; ++j) acc[j] += mv * wr[j];
  }
#pragma unroll
  for (int j = 0; j < 32; ++j)
    pmu[((size_t)(b * ATTN + jt * 32 + j)) * TENC + tt] = f2bf(acc[j]);
}

// ---------------- persistent cooperative decoder ----------------
union Scr {
  struct { uint32_t xs[2][1088]; float zr[1024]; } z;           // 12,800 B
  struct {
    float ah[1024];
    union { float pqp[1024]; float cp[2][512]; } u;
    float pq[128];
    float e_l[256];
    float red[32];
    float smax, sinv;
  } at;                                                          // 9,864 B
  struct { float xl[1536]; float part[12 * 81]; } out;           // 10,032 B
};

struct KArgs {
  const float *memory; const int *mlen;
  const float *aWih, *aWhh, *ab;
  const float *Wq, *vw, *convW, *ldW;
  const float *dWih, *dWhh, *db;
  const float *projW, *projB, *gateW, *gateB;
  const uint32_t *preTuP; const u16 *pmu;
  uint32_t *x1h, *x2h;
  float *ahf, *ctxf, *dhf;
  unsigned int *bar;
  float *mel, *gate, *algn;
};

__device__ inline void do_out(const KArgs &A, Scr &s, int b, int tm, int tid) {
  s.out.xl[tid] = cload(A.dhf + (size_t)tid * 16 + b);
  if (tid < 512) s.out.xl[1024 + tid] = cload(A.ctxf + (size_t)(tm & 1) * 8192 + tid * 16 + b);
  __syncthreads();
  if (tid < 960) {
    int col = tid % 80, kc = tid / 80;
    const float *wp = A.projW + (size_t)(kc * 128) * 80 + col;
    const float *xk = s.out.xl + kc * 128;
    float a = 0.f;
#pragma unroll 4
    for (int kk = 0; kk < 128; ++kk) a += xk[kk] * wp[(size_t)kk * 80];
    s.out.part[kc * 81 + col] = a;
  } else if (tid < 972) {
    int kc = tid - 960;
    const float *xk = s.out.xl + kc * 128;
    const float *gk = A.gateW + kc * 128;
    float a = 0.f;
#pragma unroll 4
    for (int kk = 0; kk < 128; ++kk) a += xk[kk] * gk[kk];
    s.out.part[kc * 81 + 80] = a;
  }
  __syncthreads();
  if (tid < 81) {
    float sum = 0.f;
#pragma unroll
    for (int kc = 0; kc < 12; ++kc) sum += s.out.part[kc * 81 + tid];
    if (tid < 80) A.mel[((size_t)b * 80 + tid) * TDEC + tm] = sum + A.projB[tid];
    else          A.gate[(size_t)b * TDEC + tm] = sum + A.gateB[0];
  }
}

// grid = 256 blocks x 1024 thr, 1 block/CU.
// LDS: w1h 57,600 + w2h 82,176 + awp 2,304 + Scr 12,800 = 154,880 B.
__global__ __launch_bounds__(NTHR) void k_persist(KArgs A) {
  __shared__ uint32_t w1h[16 * 900];    // z1 weights fp16 pairs, [cl][k2] (pad 4)
  __shared__ uint32_t w2h[16 * 1284];   // z2 weights, [cl][k2] (pad 4)
  __shared__ float awA[288], awC[288];  // persistent attention state (pad 16 each side)
  __shared__ Scr s;
  const int cb = blockIdx.x;
  const int tid = threadIdx.x;

  // one-time: gather this block's 16 columns (4 units x 4 gates), full K, fp16 pairs
  for (int i = tid; i < 16 * 896; i += NTHR) {
    int k2 = i >> 4, cl = i & 15;
    int gcol = cb * 4 + (cl & 3) + (cl >> 2) * 1024;
    int r0 = k2 * 2;
    float f0 = (r0 < 768) ? A.aWih[(size_t)r0 * 4096 + gcol]
                          : A.aWhh[(size_t)(r0 - 768) * 4096 + gcol];
    float f1 = (r0 + 1 < 768) ? A.aWih[(size_t)(r0 + 1) * 4096 + gcol]
                              : A.aWhh[(size_t)(r0 - 767) * 4096 + gcol];
    w1h[cl * 900 + k2] = packh2(f0, f1);
  }
  for (int i = tid; i < 16 * 1280; i += NTHR) {
    int k2 = i >> 4, cl = i & 15;
    int gcol = cb * 4 + (cl & 3) + (cl >> 2) * 1024;
    int r0 = k2 * 2;
    float f0 = (r0 < 1536) ? A.dWih[(size_t)r0 * 4096 + gcol]
                           : A.dWhh[(size_t)(r0 - 1536) * 4096 + gcol];
    float f1 = (r0 + 1 < 1536) ? A.dWih[(size_t)(r0 + 1) * 4096 + gcol]
                               : A.dWhh[(size_t)(r0 - 1535) * 4096 + gcol];
    w2h[cl * 1284 + k2] = packh2(f0, f1);
  }
  if (tid < 288) { awA[tid] = 0.f; awC[tid] = 0.f; }
  __syncthreads();

  const int cl = tid & 15, bq = (tid >> 4) & 15, sl = tid >> 8;  // GEMM mapping
  const int k2s = tid >> 4, bs = tid & 15;                        // stage mapping
  float acR = 0.f, dcR = 0.f;                                     // LSTM cell state (tid<64)
  unsigned int ep = 0;

  for (int t = 0; t < TDEC; ++t) {
    const int p = t & 1, rp = p ^ 1;

    // ============ P1: Z1 full-K GEMM + aLSTM (all 256 blocks) ============
    {
      uint32_t v[14];
#pragma unroll
      for (int c = 0; c < 14; ++c) {
        int K2 = c * 64 + k2s;
        int pp = K2 < 384 ? K2 : 384 + rp * 512 + (K2 - 384);
        v[c] = cload_u32(A.x1h + (size_t)pp * 16 + bs);
      }
      float acc = 0.f;
      const uint32_t *wcol = w1h + cl * 900;
#pragma unroll
      for (int c = 0; c < 14; ++c) {
        s.z.xs[c & 1][bs * 68 + k2s] = v[c];
        __syncthreads();
        const uint32_t *xr = s.z.xs[c & 1] + bq * 68 + sl * 16;
        const uint32_t *wr = wcol + c * 64 + sl * 16;
#pragma unroll
        for (int kk = 0; kk < 16; kk += 4) {
          uint4 wv = *(const uint4 *)(wr + kk);
          uint4 xv = *(const uint4 *)(xr + kk);
          acc = fdot2(u2h2(wv.x), u2h2(xv.x), acc);
          acc = fdot2(u2h2(wv.y), u2h2(xv.y), acc);
          acc = fdot2(u2h2(wv.z), u2h2(xv.z), acc);
          acc = fdot2(u2h2(wv.w), u2h2(xv.w), acc);
        }
      }
      s.z.zr[sl * 256 + cl * 16 + bq] = acc;
      __syncthreads();
      if (tid < 64) {
        int ul = tid >> 4, bb = tid & 15, u = cb * 4 + ul;
        float zg4[4];
#pragma unroll
        for (int gate = 0; gate < 4; ++gate) {
          int cc = gate * 4 + ul;
          float zs = A.ab[(size_t)gate * 1024 + u];
#pragma unroll
          for (int slc = 0; slc < 4; ++slc) zs += s.z.zr[slc * 256 + cc * 16 + bb];
          zg4[gate] = zs;
        }
        float cn = sigm(zg4[1]) * acR + sigm(zg4[0]) * ftanh(zg4[2]);
        float hn = sigm(zg4[3]) * ftanh(cn);
        acR = cn;
        cstore(A.ahf + (size_t)u * 16 + bb, hn);
        float hn2 = __shfl_down(hn, 16);
        if (!(ul & 1)) {
          uint32_t pk = packh2(hn, hn2);
          cstore_u32(A.x1h + (size_t)(384 + p * 512 + (u >> 1)) * 16 + bb, pk);
          cstore_u32(A.x2h + (size_t)(u >> 1) * 16 + bb, pk);
        }
      }
    }
    gsync(A.bar, ++ep, cb);

    // ============ P2: ATT (16) || OUT(t-1) (16) || prefetch (2) ============
    if (cb < 16) {
      int b = cb;
      int len = A.mlen[b];
      s.at.ah[tid] = cload(A.ahf + (size_t)tid * 16 + b);
      __syncthreads();
      {
        int j = tid & 127, kc = tid >> 7;
        float a = 0.f;
        const float *wq = A.Wq + (size_t)(kc * 128) * ATTN + j;
#pragma unroll 4
        for (int k = 0; k < 128; ++k) a += s.at.ah[kc * 128 + k] * wq[(size_t)k * ATTN];
        s.at.u.pqp[j * 8 + kc] = a;
      }
      __syncthreads();
      if (tid < 128) {
        float sm = 0.f;
#pragma unroll
        for (int kc = 0; kc < 8; ++kc) sm += s.at.u.pqp[tid * 8 + kc];
        s.at.pq[tid] = sm;
      }
      __syncthreads();
      int tt = tid >> 2, g = tid & 3;
      float lc[8];
#pragma unroll
      for (int f8 = 0; f8 < 8; ++f8) lc[f8] = 0.f;
      for (int k = 0; k < KSIZE; ++k) {
        float av = awA[tt + k + 1], cv = awC[tt + k + 1];
#pragma unroll
        for (int f8 = 0; f8 < 8; ++f8) {
          int f = g * 8 + f8;
          lc[f8] += av * A.convW[f * 62 + k] + cv * A.convW[f * 62 + 31 + k];
        }
      }
      float es = 0.f;
#pragma unroll
      for (int half = 0; half < 2; ++half) {
        float loc[16];
#pragma unroll
        for (int jj = 0; jj < 16; ++jj) loc[jj] = 0.f;
#pragma unroll
        for (int r = 0; r < 4; ++r) {
          int fg = g ^ r;
#pragma unroll
          for (int f8 = 0; f8 < 8; ++f8) {
            float lv = __shfl_xor(lc[f8], r);
            const float4 *lw4 =
                (const float4 *)(A.ldW + (size_t)(fg * 8 + f8) * ATTN + g * 32 + half * 16);
            float4 w0 = lw4[0], w1v = lw4[1], w2v = lw4[2], w3v = lw4[3];
            loc[0] += lv * w0.x;  loc[1] += lv * w0.y;  loc[2] += lv * w0.z;  loc[3] += lv * w0.w;
            loc[4] += lv * w1v.x; loc[5] += lv * w1v.y; loc[6] += lv * w1v.z; loc[7] += lv * w1v.w;
            loc[8] += lv * w2v.x; loc[9] += lv * w2v.y; loc[10]+= lv * w2v.z; loc[11]+= lv * w2v.w;
            loc[12]+= lv * w3v.x; loc[13]+= lv * w3v.y; loc[14]+= lv * w3v.z; loc[15]+= lv * w3v.w;
          }
        }
#pragma unroll
        for (int jj = 0; jj < 16; ++jj) {
          int j = g * 32 + half * 16 + jj;
          float sv = loc[jj] + s.at.pq[j] + bf2f(A.pmu[((size_t)(b * 128 + j)) * 256 + tt]);
          es += ftanh(sv) * A.vw[j];
        }
      }
      es += __shfl_xor(es, 1);
      es += __shfl_xor(es, 2);
      if (g == 0) s.at.e_l[tt] = (tt >= len) ? -1e9f : es;
      __syncthreads();
      if (tid < 32) {
        float m = -1e30f;
#pragma unroll
        for (int i = 0; i < 8; ++i) m = fmaxf(m, s.at.e_l[tid * 8 + i]);
        s.at.red[tid] = m;
      }
      __syncthreads();
      if (tid == 0) {
        float m = -1e30f;
        for (int i = 0; i < 32; ++i) m = fmaxf(m, s.at.red[i]);
        s.at.smax = m;
      }
      __syncthreads();
      if (tid < 256) s.at.e_l[tid] = __expf(s.at.e_l[tid] - s.at.smax);
      __syncthreads();
      if (tid < 32) {
        float sm = 0.f;
#pragma unroll
        for (int i = 0; i < 8; ++i) sm += s.at.e_l[tid * 8 + i];
        s.at.red[tid] = sm;
      }
      __syncthreads();
      if (tid == 0) {
        float sm = 0.f;
        for (int i = 0; i < 32; ++i) sm += s.at.red[i];
        s.at.sinv = 1.f / sm;
      }
      __syncthreads();
      if (tid < 256) {
        float w = s.at.e_l[tid] * s.at.sinv;
        s.at.e_l[tid] = w;
        awA[16 + tid] = w;
        awC[16 + tid] += w;
        A.algn[((size_t)b * TDEC + t) * TENC + tid] = w;
      }
      __syncthreads();
      {
        int e = tid & 511, h = tid >> 9;
        int t0 = h * 128, t1 = min(len, (h + 1) * 128);
        float a = 0.f;
        for (int ti = t0; ti < t1; ++ti)
          a += s.at.e_l[ti] * A.memory[((size_t)b * TENC + ti) * EDIM + e];
        s.at.u.cp[h][e] = a;
      }
      __syncthreads();
      if (tid < 512) {
        float v = s.at.u.cp[0][tid] + s.at.u.cp[1][tid];
        cstore(A.ctxf + (size_t)p * 8192 + tid * 16 + b, v);
        float v2 = __shfl_down(v, 1);
        if (!(tid & 1)) {
          uint32_t pk = packh2(v, v2);
          cstore_u32(A.x1h + (size_t)(128 + (tid >> 1)) * 16 + b, pk);
          cstore_u32(A.x2h + (size_t)(512 + (tid >> 1)) * 16 + b, pk);
        }
      }
    } else if (cb < 32) {
      if (t > 0) do_out(A, s, cb - 16, t - 1, tid);
    } else if (cb < 34) {
      if (t + 1 < TDEC) {
        int i = (cb - 32) * 1024 + tid;
        cstore_u32(A.x1h + i, cload_u32(A.preTuP + (size_t)(t + 1) * 2048 + i));
      }
    }
    gsync(A.bar, ++ep, cb);

    // ============ P3: Z2 full-K GEMM + dLSTM (all 256 blocks) ============
    {
      uint32_t v2[20];
#pragma unroll
      for (int c = 0; c < 20; ++c) {
        int K2 = c * 64 + k2s;
        int pp = K2 < 768 ? K2 : 768 + rp * 512 + (K2 - 768);
        v2[c] = cload_u32(A.x2h + (size_t)pp * 16 + bs);
      }
      float acc = 0.f;
      const uint32_t *wcol = w2h + cl * 1284;
#pragma unroll
      for (int c = 0; c < 20; ++c) {
        s.z.xs[c & 1][bs * 68 + k2s] = v2[c];
        __syncthreads();
        const uint32_t *xr = s.z.xs[c & 1] + bq * 68 + sl * 16;
        const uint32_t *wr = wcol + c * 64 + sl * 16;
#pragma unroll
        for (int kk = 0; kk < 16; kk += 4) {
          uint4 wv = *(const uint4 *)(wr + kk);
          uint4 xv = *(const uint4 *)(xr + kk);
          acc = fdot2(u2h2(wv.x), u2h2(xv.x), acc);
          acc = fdot2(u2h2(wv.y), u2h2(xv.y), acc);
          acc = fdot2(u2h2(wv.z), u2h2(xv.z), acc);
          acc = fdot2(u2h2(wv.w), u2h2(xv.w), acc);
        }
      }
      s.z.zr[sl * 256 + cl * 16 + bq] = acc;
      __syncthreads();
      if (tid < 64) {
        int ul = tid >> 4, bb = tid & 15, u = cb * 4 + ul;
        float zg4[4];
#pragma unroll
        for (int gate = 0; gate < 4; ++gate) {
          int cc = gate * 4 + ul;
          float zs = A.db[(size_t)gate * 1024 + u];
#pragma unroll
          for (int slc = 0; slc < 4; ++slc) zs += s.z.zr[slc * 256 + cc * 16 + bb];
          zg4[gate] = zs;
        }
        float cn = sigm(zg4[1]) * dcR + sigm(zg4[0]) * ftanh(zg4[2]);
        float hn = sigm(zg4[3]) * ftanh(cn);
        dcR = cn;
        cstore(A.dhf + (size_t)u * 16 + bb, hn);
        float hn2 = __shfl_down(hn, 16);
        if (!(ul & 1))
          cstore_u32(A.x2h + (size_t)(768 + p * 512 + (u >> 1)) * 16 + bb, packh2(hn, hn2));
      }
    }
    gsync(A.bar, ++ep, cb);
  }

  // tail: final projection for t = TDEC-1
  if (cb >= 16 && cb < 32) do_out(A, s, cb - 16, TDEC - 1, tid);
}

extern "C" void kernel_launch(void *const *d_in, const int *in_sizes, int n_in,
                              void *d_out, int out_size, void *d_ws, size_t ws_size,
                              hipStream_t stream) {
  (void)in_sizes; (void)n_in; (void)out_size; (void)ws_size;
  const float *memory = (const float *)d_in[0];
  const float *dec_in = (const float *)d_in[1];
  const int   *mlen   = (const int *)d_in[2];
  const float *pw1    = (const float *)d_in[3];
  const float *pw2    = (const float *)d_in[4];
  const float *aWih   = (const float *)d_in[5];
  const float *aWhh   = (const float *)d_in[6];
  const float *ab     = (const float *)d_in[7];
  const float *wq     = (const float *)d_in[8];
  const float *wmem   = (const float *)d_in[9];
  const float *vw     = (const float *)d_in[10];
  const float *convW  = (const float *)d_in[11];
  const float *ldW    = (const float *)d_in[12];
  const float *dWih   = (const float *)d_in[13];
  const float *dWhh   = (const float *)d_in[14];
  const float *db     = (const float *)d_in[15];
  const float *projW  = (const float *)d_in[16];
  const float *projB  = (const float *)d_in[17];
  const float *gateW  = (const float *)d_in[18];
  const float *gateB  = (const float *)d_in[19];

  float *out_mel  = (float *)d_out;
  float *out_gate = out_mel + (size_t)16 * 80 * 200;
  float *out_algn = out_gate + (size_t)16 * 200;

  float *ws = (float *)d_ws;
  uint32_t *x1h    = (uint32_t *)(ws + OFF_X1H);
  uint32_t *x2h    = (uint32_t *)(ws + OFF_X2H);
  float    *ahf    = ws + OFF_AHF;
  float    *ctxf   = ws + OFF_CTXF;
  float    *dhf    = ws + OFF_DHF;
  unsigned int *bar = (unsigned int *)(ws + OFF_BAR);
  uint32_t *preTuP = (uint32_t *)(ws + OFF_PRETU);
  u16      *pmu    = (u16 *)(ws + OFF_PMU);
  u16      *x1u    = (u16 *)(ws + OFF_X1U);

  hipMemsetAsync(ws, 0, STATE_F * sizeof(float), stream);
  hipMemsetAsync(bar, 0, 2048 * sizeof(unsigned int), stream);

  uint32_t K1a, K1b, K2a, K2b;
  tf2x32(0u, 42u, 0u, 0u, K1a, K1b);
  tf2x32(0u, 42u, 0u, 1u, K2a, K2b);

  k_prenet1<<<TDEC * BB, 256, 0, stream>>>(dec_in, pw1, x1u, K1a, K1b);
  k_prenet2<<<TDEC * BB, 256, 0, stream>>>(x1u, pw2, preTuP, x1h, K2a, K2b);
  k_pm<<<64, 256, 0, stream>>>(memory, wmem, pmu);

  KArgs ka;
  ka.memory = memory; ka.mlen = mlen;
  ka.aWih = aWih; ka.aWhh = aWhh; ka.ab = ab;
  ka.Wq = wq; ka.vw = vw; ka.convW = convW; ka.ldW = ldW;
  ka.dWih = dWih; ka.dWhh = dWhh; ka.db = db;
  ka.projW = projW; ka.projB = projB; ka.gateW = gateW; ka.gateB = gateB;
  ka.preTuP = preTuP; ka.pmu = pmu;
  ka.x1h = x1h; ka.x2h = x2h;
  ka.ahf = ahf; ka.ctxf = ctxf; ka.dhf = dhf;
  ka.bar = bar;
  ka.mel = out_mel; ka.gate = out_gate; ka.algn = out_algn;

  void *kp[] = { &ka };
  hipLaunchCooperativeKernel((void *)k_persist, dim3(NBLK), dim3(NTHR), kp, 0, stream);
}

// Round 7
// 25437.918 us; speedup vs baseline: 2.2701x; 2.2701x over previous
//
#include <hip/hip_runtime.h>
#include <stdint.h>

typedef unsigned short u16;
typedef _Float16 h2f16 __attribute__((ext_vector_type(2)));

#define BB    16
#define TENC  256
#define TDEC  200
#define NMELS 80
#define EDIM  512
#define PREN  256
#define ARN   1024
#define ATTN  128
#define NFILT 32
#define KSIZE 31

#define NBLK  256
#define NTHR  1024

// ---- ws layout (f32 slots); end 1,812,480 f < proven 1,839,104 f ----
#define OFF_AW     0          // 4096
#define OFF_AWC    4096       // 4096
#define OFF_AC     8192       // 16384
#define OFF_DC     24576      // 16384
#define OFF_XCAT1  40960      // 2304 rows x16 = 36864  [preA 256|preB 256|ctx 512|ah 1024]
#define OFF_XCAT2  77824      // 2560 rows x16 = 40960  [ah 1024|ctx 512|dh 1024]
#define STATE_F    118784
#define OFF_PRETU  118784     // u16[819200] pre bf16 [t][j*16+b]  (409600 f slots)
#define OFF_PMU    528384     // u16[524288] pm bf16 [b][j][tt]    (262144 f slots)
#define OFF_Z1     790528     // f32 7*16*4096 = 458752  z1 split-K partials
#define OFF_Z2     1249280    // f32 8*16*4096 = 524288  z2 split-K partials
#define OFF_PQP    1773568    // f32 16*16*128 = 32768
#define OFF_EBUF   1806336    // f32 16*256 = 4096
#define OFF_BAR    1810432    // u32[2048] hierarchical barrier

__host__ __device__ inline void tf2x32(uint32_t k0, uint32_t k1, uint32_t x0, uint32_t x1,
                                       uint32_t &y0, uint32_t &y1) {
  uint32_t ks2 = k0 ^ k1 ^ 0x1BD11BDAu;
  x0 += k0; x1 += k1;
  const int R0[4] = {13, 15, 26, 6};
  const int R1[4] = {17, 29, 16, 24};
#pragma unroll
  for (int g = 0; g < 5; ++g) {
    const int *R = (g & 1) ? R1 : R0;
#pragma unroll
    for (int i = 0; i < 4; ++i) {
      x0 += x1;
      x1 = (x1 << R[i]) | (x1 >> (32 - R[i]));
      x1 ^= x0;
    }
    switch (g) {
      case 0: x0 += k1;  x1 += ks2 + 1u; break;
      case 1: x0 += ks2; x1 += k0 + 2u;  break;
      case 2: x0 += k0;  x1 += k1 + 3u;  break;
      case 3: x0 += k1;  x1 += ks2 + 4u; break;
      case 4: x0 += ks2; x1 += k0 + 5u;  break;
    }
  }
  y0 = x0; y1 = x1;
}

__device__ inline bool keep_mask(uint32_t k0, uint32_t k1, uint32_t idx) {
  uint32_t y0, y1;
  tf2x32(k0, k1, 0u, idx, y0, y1);
  return (((y0 ^ y1) >> 31) == 0u);
}

__device__ inline float bf2f(u16 v) {
  union { uint32_t u; float f; } x;
  x.u = ((uint32_t)v) << 16;
  return x.f;
}
__device__ inline u16 f2bf(float f) {
  union { float f; uint32_t u; } x;
  x.f = f;
  uint32_t r = ((x.u >> 16) & 1u) + 0x7FFFu;
  return (u16)((x.u + r) >> 16);
}
__device__ inline float sigm(float x) { return 1.f / (1.f + __expf(-x)); }
__device__ inline float ftanh(float x) {
  x = fminf(fmaxf(x, -15.f), 15.f);
  float e = __expf(2.f * x);
  return (e - 1.f) / (e + 1.f);
}

__device__ inline uint32_t packh2(float a, float b) {
  h2f16 h; h[0] = (_Float16)a; h[1] = (_Float16)b;
  union { h2f16 h; uint32_t u; } x; x.h = h; return x.u;
}
__device__ inline h2f16 u2h2(uint32_t u) {
  union { uint32_t u; h2f16 h; } x; x.u = u; return x.h;
}
__device__ inline float fdot2(h2f16 a, h2f16 b, float c) {
#if __has_builtin(__builtin_amdgcn_fdot2)
  return __builtin_amdgcn_fdot2(a, b, c, false);
#else
  return (float)a[0] * (float)b[0] + (float)a[1] * (float)b[1] + c;
#endif
}

// ---- coherent (LLC) access, agent scope, relaxed (zero cache maintenance) ----
__device__ inline float cload(const float *p) {
  uint32_t u = __hip_atomic_load((const uint32_t *)p, __ATOMIC_RELAXED,
                                 __HIP_MEMORY_SCOPE_AGENT);
  union { uint32_t u; float f; } x; x.u = u; return x.f;
}
__device__ inline void cstore(float *p, float v) {
  union { float f; uint32_t u; } x; x.f = v;
  __hip_atomic_store((uint32_t *)p, x.u, __ATOMIC_RELAXED,
                     __HIP_MEMORY_SCOPE_AGENT);
}
__device__ inline void cload8(const float *p, float &a, float &b) {
  unsigned long long u = __hip_atomic_load((const unsigned long long *)p,
                                           __ATOMIC_RELAXED,
                                           __HIP_MEMORY_SCOPE_AGENT);
  union { unsigned long long u; float f[2]; } x; x.u = u;
  a = x.f[0]; b = x.f[1];
}

// ---- fence-free hierarchical epoch barrier (s_sleep(16) backoff) ----
__device__ inline void gsync(unsigned int *bar, unsigned int e, int cb) {
  __syncthreads();
  if (threadIdx.x == 0) {
    asm volatile("s_waitcnt vmcnt(0)" ::: "memory");
    int g = cb & 7;
    unsigned int *arr = bar + g * 64;
    unsigned int *gct = bar + 512;
    unsigned int *rel = bar + 576 + g * 64;
    unsigned int old = __hip_atomic_fetch_add(arr, 1u, __ATOMIC_RELAXED,
                                              __HIP_MEMORY_SCOPE_AGENT);
    if (old == e * 32u - 1u) {
      unsigned int o2 = __hip_atomic_fetch_add(gct, 1u, __ATOMIC_RELAXED,
                                               __HIP_MEMORY_SCOPE_AGENT);
      if (o2 == e * 8u - 1u) {
#pragma unroll
        for (int g2 = 0; g2 < 8; ++g2)
          __hip_atomic_store(bar + 576 + g2 * 64, e, __ATOMIC_RELAXED,
                             __HIP_MEMORY_SCOPE_AGENT);
      }
    }
    while (__hip_atomic_load(rel, __ATOMIC_RELAXED, __HIP_MEMORY_SCOPE_AGENT) < e)
      __builtin_amdgcn_s_sleep(16);
  }
  __syncthreads();
}

// ---------------- setup kernels (one-time) ----------------
__global__ __launch_bounds__(256) void k_prenet1(const float *__restrict__ dec_in,
                                                 const float *__restrict__ W1,
                                                 u16 *__restrict__ x1,
                                                 uint32_t k0, uint32_t k1) {
  int bid = blockIdx.x;
  int t = bid >> 4, b = bid & 15;
  int tid = threadIdx.x;
  __shared__ float di[NMELS];
  if (tid < NMELS)
    di[tid] = (t == 0) ? 0.f : dec_in[((size_t)b * NMELS + tid) * TDEC + (t - 1)];
  __syncthreads();
  int j = tid;
  float acc = 0.f;
#pragma unroll 4
  for (int m = 0; m < NMELS; ++m) acc += di[m] * W1[(size_t)m * PREN + j];
  acc = fmaxf(acc, 0.f);
  uint32_t idx = ((uint32_t)(t * BB + b)) * PREN + (uint32_t)j;
  acc = keep_mask(k0, k1, idx) ? acc * 2.f : 0.f;
  x1[(t * BB + b) * PREN + j] = f2bf(acc);
}

__global__ __launch_bounds__(256) void k_prenet2(const u16 *__restrict__ x1,
                                                 const float *__restrict__ W2,
                                                 u16 *__restrict__ preTu,
                                                 float *__restrict__ xpre0,
                                                 uint32_t k0, uint32_t k1) {
  int bid = blockIdx.x;
  int t = bid >> 4, b = bid & 15;
  int tid = threadIdx.x;
  __shared__ float xl[PREN];
  xl[tid] = bf2f(x1[(t * BB + b) * PREN + tid]);
  __syncthreads();
  int j = tid;
  float acc = 0.f;
#pragma unroll 4
  for (int k = 0; k < PREN; ++k) acc += xl[k] * W2[(size_t)k * PREN + j];
  acc = fmaxf(acc, 0.f);
  uint32_t idx = ((uint32_t)(t * BB + b)) * PREN + (uint32_t)j;
  acc = keep_mask(k0, k1, idx) ? acc * 2.f : 0.f;
  preTu[(size_t)t * 4096 + j * 16 + b] = f2bf(acc);
  if (t == 0) xpre0[j * 16 + b] = acc;      // preA region (rows 0-255)
}

__global__ __launch_bounds__(256) void k_pm(const float *__restrict__ memory,
                                            const float *__restrict__ Wmem,
                                            u16 *__restrict__ pmu) {
  int p = blockIdx.x;
  int b = p & 15, jt = p >> 4;
  int tt = threadIdx.x;
  float acc[32];
#pragma unroll
  for (int j = 0; j < 32; ++j) acc[j] = 0.f;
  const float *mrow = memory + ((size_t)b * TENC + tt) * EDIM;
  const float *wb = Wmem + jt * 32;
  for (int e = 0; e < EDIM; ++e) {
    float mv = mrow[e];
    const float *wr = wb + (size_t)e * ATTN;
#pragma unroll
    for (int j = 0; j < 32; ++j) acc[j] += mv * wr[j];
  }
#pragma unroll
  for (int j = 0; j < 32; ++j)
    pmu[((size_t)(b * ATTN + jt * 32 + j)) * TENC + tt] = f2bf(acc[j]);
}

// ---------------- persistent cooperative decoder ----------------
struct F2 { float x, y; };

union Scr {
  struct { uint32_t xs1[128 * 16]; } z1s;                       //  8,192 B
  struct { uint32_t xs2[160 * 16]; } z2s;                       // 10,240 B
  struct { F2 part[16 * 64]; float hn[64]; } al;                //  8,448 B
  struct {
    float aw_l[96], awc_l[96];
    float lc[64 * 33];
    float pq[128];
    float ep[64 * 17];
  } att;                                                        // 14,080 B
  struct { float e_l[256]; float red[32]; float smax, sinv; float part[32 * 33]; } ctc;
  struct { float xl[1536]; float part[12 * 81]; } out;          // 10,032 B
};

struct KArgs {
  const float *memory; const int *mlen;
  const float *aWih, *aWhh, *ab;
  const float *Wq, *vw, *convW, *ldW;
  const float *dWih, *dWhh, *db;
  const float *projW, *projB, *gateW, *gateB;
  const u16 *preTu, *pmu;
  float *aw, *awc, *ac, *dc, *xcat1, *xcat2, *z1, *z2, *pqp, *ebuf;
  unsigned int *bar;
  float *mel, *gate, *algn;
};

// OUT: dLSTM from z2 partials + projection (blocks 224-239, b = cb-224)
__device__ inline void do_out(const KArgs &A, Scr &s, int b, int tm, int tid) {
  {
    int u = tid;
    float zi = 0.f, zf = 0.f, zg = 0.f, zo = 0.f;
    for (int kc = 0; kc < 8; ++kc) {
      const float *zb = A.z2 + ((size_t)(kc * 16 + b)) * 4096;
      zi += cload(zb + u); zf += cload(zb + u + 1024);
      zg += cload(zb + u + 2048); zo += cload(zb + u + 3072);
    }
    zi += A.db[u]; zf += A.db[u + 1024]; zg += A.db[u + 2048]; zo += A.db[u + 3072];
    float cn = sigm(zf) * A.dc[b * 1024 + u] + sigm(zi) * ftanh(zg);
    float hn = sigm(zo) * ftanh(cn);
    A.dc[b * 1024 + u] = cn;
    cstore(&A.xcat2[(size_t)(1536 + u) * 16 + b], hn);
    s.out.xl[u] = hn;
  }
  if (tid < 512) s.out.xl[1024 + tid] = cload(&A.xcat2[(size_t)(1024 + tid) * 16 + b]);
  __syncthreads();
  if (tid < 960) {
    int col = tid % 80, kc = tid / 80;          // 12 k-groups x 128
    const float *wp = A.projW + (size_t)(kc * 128) * 80 + col;
    const float *xk = s.out.xl + kc * 128;
    float a = 0.f;
#pragma unroll 4
    for (int kk = 0; kk < 128; ++kk) a += xk[kk] * wp[(size_t)kk * 80];
    s.out.part[kc * 81 + col] = a;
  } else if (tid < 972) {
    int kc = tid - 960;
    const float *xk = s.out.xl + kc * 128;
    const float *gk = A.gateW + kc * 128;
    float a = 0.f;
#pragma unroll 4
    for (int kk = 0; kk < 128; ++kk) a += xk[kk] * gk[kk];
    s.out.part[kc * 81 + 80] = a;
  }
  __syncthreads();
  if (tid < 81) {
    float sum = 0.f;
#pragma unroll
    for (int kc = 0; kc < 12; ++kc) sum += s.out.part[kc * 81 + tid];
    if (tid < 80) A.mel[((size_t)b * 80 + tid) * TDEC + tm] = sum + A.projB[tid];
    else          A.gate[(size_t)b * TDEC + tm] = sum + A.gateB[0];
  }
  __syncthreads();
}

// grid = 256 x 1024, 1 block/CU. LDS: w1h 65,536 + w2h 81,920 + Scr 14,080 = 161,536 B.
__global__ __launch_bounds__(NTHR) void k_persist(KArgs A) {
  __shared__ uint32_t w1h[128 * 128];   // z1 weight slice fp16 pairs [k2][col]
  __shared__ uint32_t w2h[160 * 128];   // z2 weight slice
  __shared__ Scr s;
  const int cb = blockIdx.x;
  const int tid = threadIdx.x;
  const int q = cb >> 5;                // z1: 0-6 (224 blk); z2: 0-7 (256 blk)
  const int c = cb & 31;

  // one-time weight staging (fp16 pairs)
  if (cb < 224) {
    for (int i = tid; i < 128 * 128; i += NTHR) {
      int k2 = i >> 7, col = i & 127, cg = c * 128 + col;
      int r0 = q * 256 + k2 * 2;        // r0 even; Wih/Whh boundary 768 even
      float f0 = (r0 < 768) ? A.aWih[(size_t)r0 * 4096 + cg]
                            : A.aWhh[(size_t)(r0 - 768) * 4096 + cg];
      float f1 = (r0 < 768) ? A.aWih[(size_t)(r0 + 1) * 4096 + cg]
                            : A.aWhh[(size_t)(r0 - 767) * 4096 + cg];
      w1h[i] = packh2(f0, f1);
    }
  }
  for (int i = tid; i < 160 * 128; i += NTHR) {
    int k2 = i >> 7, col = i & 127, cg = c * 128 + col;
    int r0 = q * 320 + k2 * 2;          // boundary 1536 even
    float f0 = (r0 < 1536) ? A.dWih[(size_t)r0 * 4096 + cg]
                           : A.dWhh[(size_t)(r0 - 1536) * 4096 + cg];
    float f1 = (r0 < 1536) ? A.dWih[(size_t)(r0 + 1) * 4096 + cg]
                           : A.dWhh[(size_t)(r0 - 1535) * 4096 + cg];
    w2h[i] = packh2(f0, f1);
  }
  __syncthreads();

  unsigned int ep = 0;
  for (int t = 0; t < TDEC; ++t) {
    const int p = t & 1;

    // ===== Seg A: Z1 (224 blk) || OUT(t-1) (16 blk) || prefetch pre(t+1) (2 blk) =====
    if (cb < 224) {
      {
        int i = tid;                    // 128*8 == 1024, one per thread
        int k2 = i >> 3, b2 = (i & 7) * 2;
        int lr = q * 256 + k2 * 2;      // logical row; pairs never cross region bounds
        int pr = (lr < 256) ? p * 256 + lr : 256 + lr;   // pre ping-pong remap
        const float *xr = A.xcat1 + (size_t)pr * 16 + b2;
        float r0a, r0b, r1a, r1b;
        cload8(xr, r0a, r0b);
        cload8(xr + 16, r1a, r1b);
        s.z1s.xs1[k2 * 16 + b2]     = packh2(r0a, r1a);
        s.z1s.xs1[k2 * 16 + b2 + 1] = packh2(r0b, r1b);
      }
      __syncthreads();
      int col = tid & 127, bg = tid >> 7;
      float a0 = 0.f, a1 = 0.f;
      const uint32_t *wp = w1h + col;
      const uint32_t *xp = s.z1s.xs1 + bg * 2;
#pragma unroll 8
      for (int k2 = 0; k2 < 128; ++k2) {
        h2f16 w = u2h2(wp[k2 * 128]);
        a0 = fdot2(w, u2h2(xp[k2 * 16]), a0);
        a1 = fdot2(w, u2h2(xp[k2 * 16 + 1]), a1);
      }
      int cg = c * 128 + col;
      cstore(&A.z1[((size_t)q * 16 + bg * 2    ) * 4096 + cg], a0);
      cstore(&A.z1[((size_t)q * 16 + bg * 2 + 1) * 4096 + cg], a1);
    } else if (cb < 240) {
      if (t > 0) do_out(A, s, cb - 224, t - 1, tid);
    } else if (cb < 242) {
      if (t + 1 < TDEC) {
        int base = ((t + 1) & 1) * 4096;               // preA/preB f32 offset
        int i0 = (cb - 240) * 1024 + tid;
        cstore(&A.xcat1[base + i0],
               bf2f(A.preTu[(size_t)(t + 1) * 4096 + i0]));
        cstore(&A.xcat1[base + i0 + 2048],
               bf2f(A.preTu[(size_t)(t + 1) * 4096 + i0 + 2048]));
      }
    }
    gsync(A.bar, ++ep, cb);

    // ===== Seg B: A-LSTM + pq partials (all 256: 16b x 16ug) =====
    {
      int b = cb & 15, ug = cb >> 4;
      {
        int u_l = tid & 63, j = tid >> 6;
        int kc = j & 7, gh = j >> 3;
        F2 pv; pv.x = 0.f; pv.y = 0.f;
        if (kc < 7) {
          const float *zb = A.z1 + ((size_t)(kc * 16 + b)) * 4096 + gh * 2048 + (ug * 64 + u_l);
          pv.x = cload(zb); pv.y = cload(zb + 1024);
        }
        s.al.part[j * 64 + u_l] = pv;
      }
      __syncthreads();
      if (tid < 64) {
        int uu = ug * 64 + tid;
        float g0 = 0.f, g1 = 0.f, g2 = 0.f, g3 = 0.f;
#pragma unroll
        for (int kc = 0; kc < 8; ++kc) {
          F2 v0 = s.al.part[kc * 64 + tid];
          F2 v1 = s.al.part[(8 + kc) * 64 + tid];
          g0 += v0.x; g1 += v0.y; g2 += v1.x; g3 += v1.y;
        }
        float zi = g0 + A.ab[uu], zf = g1 + A.ab[1024 + uu];
        float zg = g2 + A.ab[2048 + uu], zo = g3 + A.ab[3072 + uu];
        float cn = sigm(zf) * A.ac[b * 1024 + uu] + sigm(zi) * ftanh(zg);
        float hn = sigm(zo) * ftanh(cn);
        A.ac[b * 1024 + uu] = cn;
        cstore(&A.xcat1[(size_t)(1024 + uu) * 16 + b], hn);
        cstore(&A.xcat2[(size_t)uu * 16 + b], hn);
        s.al.hn[tid] = hn;
      }
      __syncthreads();
      if (tid < 128) {
        float a = 0.f;
        const float *wq = A.Wq + (size_t)(ug * 64) * 128 + tid;
#pragma unroll 4
        for (int k = 0; k < 64; ++k) a += s.al.hn[k] * wq[(size_t)k * 128];
        cstore(&A.pqp[(size_t)(b * 16 + ug) * 128 + tid], a);
      }
    }
    gsync(A.bar, ++ep, cb);

    // ===== Seg C: ATT-A conv + energies (64 blk: 16b x 4 tt-slabs) =====
    if (cb < 64) {
      int b = cb & 15, tq = cb >> 4;
      if (tid < 96) {
        int gi = tq * 64 - 16 + tid;
        bool ok = (gi >= 0 && gi < 256);
        s.att.aw_l[tid]  = ok ? cload(&A.aw[b * 256 + gi])  : 0.f;
        s.att.awc_l[tid] = ok ? cload(&A.awc[b * 256 + gi]) : 0.f;
      }
      if (tid >= 128 && tid < 256) {
        int j = tid - 128;
        float sum = 0.f;
#pragma unroll
        for (int g = 0; g < 16; ++g) sum += cload(&A.pqp[(size_t)(b * 16 + g) * 128 + j]);
        s.att.pq[j] = sum;
      }
      __syncthreads();
      {
        int tt_l = tid & 63, fg = tid >> 6;
        int f0 = fg * 2;
        float a0 = 0.f, a1 = 0.f;
        for (int k = 0; k < KSIZE; ++k) {
          float av = s.att.aw_l[tt_l + k + 1];
          float cv = s.att.awc_l[tt_l + k + 1];
          a0 += av * A.convW[f0 * 62 + k]       + cv * A.convW[f0 * 62 + 31 + k];
          a1 += av * A.convW[(f0 + 1) * 62 + k] + cv * A.convW[(f0 + 1) * 62 + 31 + k];
        }
        s.att.lc[tt_l * 33 + f0]     = a0;
        s.att.lc[tt_l * 33 + f0 + 1] = a1;
      }
      __syncthreads();
      {
        int tt_l = tid & 63, g = tid >> 6;
        int tt = tq * 64 + tt_l, j0 = g * 8;
        float acc[8] = {0, 0, 0, 0, 0, 0, 0, 0};
        for (int f = 0; f < NFILT; ++f) {
          float lv = s.att.lc[tt_l * 33 + f];
          const float *lw = A.ldW + f * ATTN + j0;
#pragma unroll
          for (int jj = 0; jj < 8; ++jj) acc[jj] += lv * lw[jj];
        }
        float es = 0.f;
#pragma unroll
        for (int jj = 0; jj < 8; ++jj) {
          float sv = acc[jj] + s.att.pq[j0 + jj]
                   + bf2f(A.pmu[((size_t)(b * 128 + j0 + jj)) * 256 + tt]);
          es += ftanh(sv) * A.vw[j0 + jj];
        }
        s.att.ep[tt_l * 17 + g] = es;
      }
      __syncthreads();
      if (tid < 64) {
        float e = 0.f;
#pragma unroll
        for (int g = 0; g < 16; ++g) e += s.att.ep[tid * 17 + g];
        int tt = tq * 64 + tid;
        if (tt >= A.mlen[b]) e = -1e9f;
        cstore(&A.ebuf[b * 256 + tt], e);
      }
    }
    gsync(A.bar, ++ep, cb);

    // ===== Seg D: softmax (replicated) + ctx (all 256: 16b x 16 e-chunks) =====
    {
      int b = cb & 15, ec = cb >> 4;
      if (tid < 256) s.ctc.e_l[tid] = cload(&A.ebuf[b * 256 + tid]);
      __syncthreads();
      if (tid < 32) {
        float m = -1e30f;
#pragma unroll
        for (int i = 0; i < 8; ++i) m = fmaxf(m, s.ctc.e_l[tid * 8 + i]);
        s.ctc.red[tid] = m;
      }
      __syncthreads();
      if (tid == 0) {
        float m = -1e30f;
        for (int i = 0; i < 32; ++i) m = fmaxf(m, s.ctc.red[i]);
        s.ctc.smax = m;
      }
      __syncthreads();
      if (tid < 256) s.ctc.e_l[tid] = __expf(s.ctc.e_l[tid] - s.ctc.smax);
      __syncthreads();
      if (tid < 32) {
        float sm = 0.f;
#pragma unroll
        for (int i = 0; i < 8; ++i) sm += s.ctc.e_l[tid * 8 + i];
        s.ctc.red[tid] = sm;
      }
      __syncthreads();
      if (tid == 0) {
        float sm = 0.f;
        for (int i = 0; i < 32; ++i) sm += s.ctc.red[i];
        s.ctc.sinv = 1.f / sm;
      }
      __syncthreads();
      if (tid < 256) s.ctc.e_l[tid] *= s.ctc.sinv;
      __syncthreads();
      if (ec == 0 && tid < 256) {
        float w = s.ctc.e_l[tid];
        cstore(&A.aw[b * 256 + tid], w);
        cstore(&A.awc[b * 256 + tid], cload(&A.awc[b * 256 + tid]) + w);
        A.algn[((size_t)b * TDEC + t) * TENC + tid] = w;
      }
      {
        int e_l = tid & 31, sub = tid >> 5;
        const float *mp = A.memory + ((size_t)(b * 256) + sub * 8) * 512 + ec * 32 + e_l;
        float a = 0.f;
#pragma unroll
        for (int i = 0; i < 8; ++i) a += s.ctc.e_l[sub * 8 + i] * mp[(size_t)i * 512];
        s.ctc.part[e_l * 33 + sub] = a;
      }
      __syncthreads();
      if (tid < 32) {
        float sum = 0.f;
#pragma unroll
        for (int i = 0; i < 32; ++i) sum += s.ctc.part[tid * 33 + i];
        int eg = ec * 32 + tid;
        cstore(&A.xcat1[(size_t)(512 + eg) * 16 + b], sum);
        cstore(&A.xcat2[(size_t)(1024 + eg) * 16 + b], sum);
      }
    }
    gsync(A.bar, ++ep, cb);

    // ===== Seg E: Z2 (all 256: 8q x 32c, BK=160 k2) =====
    {
      for (int i = tid; i < 160 * 8; i += NTHR) {
        int k2 = i >> 3, b2 = (i & 7) * 2;
        const float *xr = A.xcat2 + (size_t)(q * 320 + k2 * 2) * 16 + b2;
        float r0a, r0b, r1a, r1b;
        cload8(xr, r0a, r0b);
        cload8(xr + 16, r1a, r1b);
        s.z2s.xs2[k2 * 16 + b2]     = packh2(r0a, r1a);
        s.z2s.xs2[k2 * 16 + b2 + 1] = packh2(r0b, r1b);
      }
      __syncthreads();
      int col = tid & 127, bg = tid >> 7;
      float a0 = 0.f, a1 = 0.f;
      const uint32_t *wp = w2h + col;
      const uint32_t *xp = s.z2s.xs2 + bg * 2;
#pragma unroll 8
      for (int k2 = 0; k2 < 160; ++k2) {
        h2f16 w = u2h2(wp[k2 * 128]);
        a0 = fdot2(w, u2h2(xp[k2 * 16]), a0);
        a1 = fdot2(w, u2h2(xp[k2 * 16 + 1]), a1);
      }
      int cg = c * 128 + col;
      cstore(&A.z2[((size_t)q * 16 + bg * 2    ) * 4096 + cg], a0);
      cstore(&A.z2[((size_t)q * 16 + bg * 2 + 1) * 4096 + cg], a1);
    }
    gsync(A.bar, ++ep, cb);
  }

  // tail: OUT for t = TDEC-1
  if (cb >= 224 && cb < 240) do_out(A, s, cb - 224, TDEC - 1, tid);
}

extern "C" void kernel_launch(void *const *d_in, const int *in_sizes, int n_in,
                              void *d_out, int out_size, void *d_ws, size_t ws_size,
                              hipStream_t stream) {
  (void)in_sizes; (void)n_in; (void)out_size; (void)ws_size;
  const float *memory = (const float *)d_in[0];
  const float *dec_in = (const float *)d_in[1];
  const int   *mlen   = (const int *)d_in[2];
  const float *pw1    = (const float *)d_in[3];
  const float *pw2    = (const float *)d_in[4];
  const float *aWih   = (const float *)d_in[5];
  const float *aWhh   = (const float *)d_in[6];
  const float *ab     = (const float *)d_in[7];
  const float *wq     = (const float *)d_in[8];
  const float *wmem   = (const float *)d_in[9];
  const float *vw     = (const float *)d_in[10];
  const float *convW  = (const float *)d_in[11];
  const float *ldW    = (const float *)d_in[12];
  const float *dWih   = (const float *)d_in[13];
  const float *dWhh   = (const float *)d_in[14];
  const float *db     = (const float *)d_in[15];
  const float *projW  = (const float *)d_in[16];
  const float *projB  = (const float *)d_in[17];
  const float *gateW  = (const float *)d_in[18];
  const float *gateB  = (const float *)d_in[19];

  float *out_mel  = (float *)d_out;
  float *out_gate = out_mel + (size_t)16 * 80 * 200;
  float *out_algn = out_gate + (size_t)16 * 200;

  float *ws = (float *)d_ws;
  float *aw    = ws + OFF_AW;
  float *awc   = ws + OFF_AWC;
  float *ac    = ws + OFF_AC;
  float *dc    = ws + OFF_DC;
  float *xcat1 = ws + OFF_XCAT1;
  float *xcat2 = ws + OFF_XCAT2;
  u16 *preTu = (u16 *)(ws + OFF_PRETU);
  u16 *pmu   = (u16 *)(ws + OFF_PMU);
  float *z1   = ws + OFF_Z1;
  float *z2   = ws + OFF_Z2;
  float *pqp  = ws + OFF_PQP;
  float *ebuf = ws + OFF_EBUF;
  unsigned int *bar = (unsigned int *)(ws + OFF_BAR);
  u16 *x1u   = (u16 *)z1;                  // prenet temp alias (pre-loop only)

  hipMemsetAsync(ws, 0, STATE_F * sizeof(float), stream);
  hipMemsetAsync(bar, 0, 2048 * sizeof(unsigned int), stream);

  uint32_t K1a, K1b, K2a, K2b;
  tf2x32(0u, 42u, 0u, 0u, K1a, K1b);
  tf2x32(0u, 42u, 0u, 1u, K2a, K2b);

  k_prenet1<<<TDEC * BB, 256, 0, stream>>>(dec_in, pw1, x1u, K1a, K1b);
  k_prenet2<<<TDEC * BB, 256, 0, stream>>>(x1u, pw2, preTu, xcat1, K2a, K2b);
  k_pm<<<64, 256, 0, stream>>>(memory, wmem, pmu);

  KArgs ka;
  ka.memory = memory; ka.mlen = mlen;
  ka.aWih = aWih; ka.aWhh = aWhh; ka.ab = ab;
  ka.Wq = wq; ka.vw = vw; ka.convW = convW; ka.ldW = ldW;
  ka.dWih = dWih; ka.dWhh = dWhh; ka.db = db;
  ka.projW = projW; ka.projB = projB; ka.gateW = gateW; ka.gateB = gateB;
  ka.preTu = preTu; ka.pmu = pmu;
  ka.aw = aw; ka.awc = awc; ka.ac = ac; ka.dc = dc;
  ka.xcat1 = xcat1; ka.xcat2 = xcat2; ka.z1 = z1; ka.z2 = z2;
  ka.pqp = pqp; ka.ebuf = ebuf;
  ka.bar = bar;
  ka.mel = out_mel; ka.gate = out_gate; ka.algn = out_algn;

  void *kp[] = { &ka };
  hipLaunchCooperativeKernel((void *)k_persist, dim3(NBLK), dim3(NTHR), kp, 0, stream);
}

// Round 8
// 25392.842 us; speedup vs baseline: 2.2741x; 1.0018x over previous
//
#include <hip/hip_runtime.h>
#include <stdint.h>

typedef unsigned short u16;
typedef _Float16 h2f16 __attribute__((ext_vector_type(2)));

#define BB    16
#define TENC  256
#define TDEC  200
#define NMELS 80
#define EDIM  512
#define PREN  256
#define ARN   1024
#define ATTN  128
#define NFILT 32
#define KSIZE 31

#define NBLK  256
#define NTHR  1024

// ---- ws layout (f32 slots); end 1,779,712 f < proven 1,839,104 f ----
#define OFF_AW     0          // 4096
#define OFF_AWC    4096       // 4096
#define OFF_AC     8192       // 16384
#define OFF_DC     24576      // 16384
#define OFF_X1P    40960      // u32[16384] fp16-pair rows [preA128|preB128|ctx256|ah512] x16
#define OFF_X2P    57344      // u32[20480] fp16-pair rows [ah512|ctx256|dh512] x16
#define OFF_CTXF   77824      // f[8192]  ctx f32 [e*16+b] (OUT projection source)
#define STATE_F    86016
#define OFF_PRETU  86016      // u32[409600] pre fp16-pairs [t][(j>>1)*16+b]
#define OFF_PMU    495616     // u16[524288] pm bf16 [b][j][tt]  (262144 f slots)
#define OFF_Z1     757760     // f32 7*16*4096 = 458752  z1 split-K partials
#define OFF_Z2     1216512    // f32 8*16*4096 = 524288  z2 split-K partials
#define OFF_PQP    1740800    // f32 16*16*128 = 32768
#define OFF_EBUF   1773568    // f32 16*256 = 4096
#define OFF_BAR    1777664    // u32[2048] hierarchical barrier

__host__ __device__ inline void tf2x32(uint32_t k0, uint32_t k1, uint32_t x0, uint32_t x1,
                                       uint32_t &y0, uint32_t &y1) {
  uint32_t ks2 = k0 ^ k1 ^ 0x1BD11BDAu;
  x0 += k0; x1 += k1;
  const int R0[4] = {13, 15, 26, 6};
  const int R1[4] = {17, 29, 16, 24};
#pragma unroll
  for (int g = 0; g < 5; ++g) {
    const int *R = (g & 1) ? R1 : R0;
#pragma unroll
    for (int i = 0; i < 4; ++i) {
      x0 += x1;
      x1 = (x1 << R[i]) | (x1 >> (32 - R[i]));
      x1 ^= x0;
    }
    switch (g) {
      case 0: x0 += k1;  x1 += ks2 + 1u; break;
      case 1: x0 += ks2; x1 += k0 + 2u;  break;
      case 2: x0 += k0;  x1 += k1 + 3u;  break;
      case 3: x0 += k1;  x1 += ks2 + 4u; break;
      case 4: x0 += ks2; x1 += k0 + 5u;  break;
    }
  }
  y0 = x0; y1 = x1;
}

__device__ inline bool keep_mask(uint32_t k0, uint32_t k1, uint32_t idx) {
  uint32_t y0, y1;
  tf2x32(k0, k1, 0u, idx, y0, y1);
  return (((y0 ^ y1) >> 31) == 0u);
}

__device__ inline float bf2f(u16 v) {
  union { uint32_t u; float f; } x;
  x.u = ((uint32_t)v) << 16;
  return x.f;
}
__device__ inline u16 f2bf(float f) {
  union { float f; uint32_t u; } x;
  x.f = f;
  uint32_t r = ((x.u >> 16) & 1u) + 0x7FFFu;
  return (u16)((x.u + r) >> 16);
}
__device__ inline float sigm(float x) { return 1.f / (1.f + __expf(-x)); }
__device__ inline float ftanh(float x) {
  x = fminf(fmaxf(x, -15.f), 15.f);
  float e = __expf(2.f * x);
  return (e - 1.f) / (e + 1.f);
}

__device__ inline uint32_t packh2(float a, float b) {
  h2f16 h; h[0] = (_Float16)a; h[1] = (_Float16)b;
  union { h2f16 h; uint32_t u; } x; x.h = h; return x.u;
}
__device__ inline h2f16 u2h2(uint32_t u) {
  union { uint32_t u; h2f16 h; } x; x.u = u; return x.h;
}
__device__ inline float fdot2(h2f16 a, h2f16 b, float c) {
#if __has_builtin(__builtin_amdgcn_fdot2)
  return __builtin_amdgcn_fdot2(a, b, c, false);
#else
  return (float)a[0] * (float)b[0] + (float)a[1] * (float)b[1] + c;
#endif
}

// ---- coherent (LLC) access, agent scope, relaxed (zero cache maintenance) ----
__device__ inline float cload(const float *p) {
  uint32_t u = __hip_atomic_load((const uint32_t *)p, __ATOMIC_RELAXED,
                                 __HIP_MEMORY_SCOPE_AGENT);
  union { uint32_t u; float f; } x; x.u = u; return x.f;
}
__device__ inline void cstore(float *p, float v) {
  union { float f; uint32_t u; } x; x.f = v;
  __hip_atomic_store((uint32_t *)p, x.u, __ATOMIC_RELAXED,
                     __HIP_MEMORY_SCOPE_AGENT);
}
__device__ inline uint32_t cload_u32(const uint32_t *p) {
  return __hip_atomic_load(p, __ATOMIC_RELAXED, __HIP_MEMORY_SCOPE_AGENT);
}
__device__ inline void cstore_u32(uint32_t *p, uint32_t v) {
  __hip_atomic_store(p, v, __ATOMIC_RELAXED, __HIP_MEMORY_SCOPE_AGENT);
}

// ---- fence-free hierarchical epoch barrier (s_sleep(16) backoff) ----
__device__ inline void gsync(unsigned int *bar, unsigned int e, int cb) {
  __syncthreads();
  if (threadIdx.x == 0) {
    asm volatile("s_waitcnt vmcnt(0)" ::: "memory");
    int g = cb & 7;
    unsigned int *arr = bar + g * 64;
    unsigned int *gct = bar + 512;
    unsigned int *rel = bar + 576 + g * 64;
    unsigned int old = __hip_atomic_fetch_add(arr, 1u, __ATOMIC_RELAXED,
                                              __HIP_MEMORY_SCOPE_AGENT);
    if (old == e * 32u - 1u) {
      unsigned int o2 = __hip_atomic_fetch_add(gct, 1u, __ATOMIC_RELAXED,
                                               __HIP_MEMORY_SCOPE_AGENT);
      if (o2 == e * 8u - 1u) {
#pragma unroll
        for (int g2 = 0; g2 < 8; ++g2)
          __hip_atomic_store(bar + 576 + g2 * 64, e, __ATOMIC_RELAXED,
                             __HIP_MEMORY_SCOPE_AGENT);
      }
    }
    while (__hip_atomic_load(rel, __ATOMIC_RELAXED, __HIP_MEMORY_SCOPE_AGENT) < e)
      __builtin_amdgcn_s_sleep(16);
  }
  __syncthreads();
}

// ---------------- setup kernels (one-time) ----------------
__global__ __launch_bounds__(256) void k_prenet1(const float *__restrict__ dec_in,
                                                 const float *__restrict__ W1,
                                                 u16 *__restrict__ x1,
                                                 uint32_t k0, uint32_t k1) {
  int bid = blockIdx.x;
  int t = bid >> 4, b = bid & 15;
  int tid = threadIdx.x;
  __shared__ float di[NMELS];
  if (tid < NMELS)
    di[tid] = (t == 0) ? 0.f : dec_in[((size_t)b * NMELS + tid) * TDEC + (t - 1)];
  __syncthreads();
  int j = tid;
  float acc = 0.f;
#pragma unroll 4
  for (int m = 0; m < NMELS; ++m) acc += di[m] * W1[(size_t)m * PREN + j];
  acc = fmaxf(acc, 0.f);
  uint32_t idx = ((uint32_t)(t * BB + b)) * PREN + (uint32_t)j;
  acc = keep_mask(k0, k1, idx) ? acc * 2.f : 0.f;
  x1[(t * BB + b) * PREN + j] = f2bf(acc);
}

__global__ __launch_bounds__(256) void k_prenet2(const u16 *__restrict__ x1,
                                                 const float *__restrict__ W2,
                                                 uint32_t *__restrict__ preTuP,
                                                 uint32_t *__restrict__ x1p,
                                                 uint32_t k0, uint32_t k1) {
  int bid = blockIdx.x;
  int t = bid >> 4, b = bid & 15;
  int tid = threadIdx.x;
  __shared__ float xl[PREN];
  xl[tid] = bf2f(x1[(t * BB + b) * PREN + tid]);
  __syncthreads();
  int j = tid;
  float acc = 0.f;
#pragma unroll 4
  for (int k = 0; k < PREN; ++k) acc += xl[k] * W2[(size_t)k * PREN + j];
  acc = fmaxf(acc, 0.f);
  uint32_t idx = ((uint32_t)(t * BB + b)) * PREN + (uint32_t)j;
  acc = keep_mask(k0, k1, idx) ? acc * 2.f : 0.f;
  float accN = __shfl_down(acc, 1);
  if (!(j & 1)) {
    uint32_t pk = packh2(acc, accN);
    preTuP[(size_t)t * 2048 + (j >> 1) * 16 + b] = pk;
    if (t == 0) x1p[(j >> 1) * 16 + b] = pk;   // preA pair-rows 0-127 (t=0 -> p=0)
  }
}

__global__ __launch_bounds__(256) void k_pm(const float *__restrict__ memory,
                                            const float *__restrict__ Wmem,
                                            u16 *__restrict__ pmu) {
  int p = blockIdx.x;
  int b = p & 15, jt = p >> 4;
  int tt = threadIdx.x;
  float acc[32];
#pragma unroll
  for (int j = 0; j < 32; ++j) acc[j] = 0.f;
  const float *mrow = memory + ((size_t)b * TENC + tt) * EDIM;
  const float *wb = Wmem + jt * 32;
  for (int e = 0; e < EDIM; ++e) {
    float mv = mrow[e];
    const float *wr = wb + (size_t)e * ATTN;
#pragma unroll
    for (int j = 0; j < 32; ++j) acc[j] += mv * wr[j];
  }
#pragma unroll
  for (int j = 0; j < 32; ++j)
    pmu[((size_t)(b * ATTN + jt * 32 + j)) * TENC + tt] = f2bf(acc[j]);
}

// ---------------- persistent cooperative decoder ----------------
struct F2 { float x, y; };

union Scr {
  struct { uint32_t xs1[128 * 16]; } z1s;                       //  8,192 B
  struct { uint32_t xs2[160 * 16]; } z2s;                       // 10,240 B
  struct { F2 part[16 * 64]; float hn[64]; } al;                //  8,448 B
  struct {
    float aw_l[96], awc_l[96];
    float lc[64 * 33];
    float pq[128];
    float ep[64 * 17];
  } att;                                                        // 14,080 B
  struct { float e_l[256]; float red[32]; float smax, sinv; float part[32 * 33]; } ctc;
  struct { float xl[1536]; float part[12 * 81]; } out;          // 10,032 B
};

struct KArgs {
  const float *memory; const int *mlen;
  const float *aWih, *aWhh, *ab;
  const float *Wq, *vw, *convW, *ldW;
  const float *dWih, *dWhh, *db;
  const float *projW, *projB, *gateW, *gateB;
  const uint32_t *preTuP; const u16 *pmu;
  uint32_t *x1p, *x2p;
  float *aw, *awc, *ac, *dc, *ctxf, *z1, *z2, *pqp, *ebuf;
  unsigned int *bar;
  float *mel, *gate, *algn;
};

// OUT: dLSTM from z2 partials + projection (blocks 224-239, b = cb-224)
__device__ inline void do_out(const KArgs &A, Scr &s, int b, int tm, int tid) {
  {
    int u = tid;
    float zi = 0.f, zf = 0.f, zg = 0.f, zo = 0.f;
    for (int kc = 0; kc < 8; ++kc) {
      const float *zb = A.z2 + ((size_t)(kc * 16 + b)) * 4096;
      zi += cload(zb + u); zf += cload(zb + u + 1024);
      zg += cload(zb + u + 2048); zo += cload(zb + u + 3072);
    }
    zi += A.db[u]; zf += A.db[u + 1024]; zg += A.db[u + 2048]; zo += A.db[u + 3072];
    float cn = sigm(zf) * A.dc[b * 1024 + u] + sigm(zi) * ftanh(zg);
    float hn = sigm(zo) * ftanh(cn);
    A.dc[b * 1024 + u] = cn;
    float hn2 = __shfl_down(hn, 1);
    if (!(tid & 1))
      cstore_u32(A.x2p + (size_t)(768 + (tid >> 1)) * 16 + b, packh2(hn, hn2));
    s.out.xl[u] = hn;
  }
  if (tid < 512) s.out.xl[1024 + tid] = cload(A.ctxf + (size_t)tid * 16 + b);
  __syncthreads();
  if (tid < 960) {
    int col = tid % 80, kc = tid / 80;          // 12 k-groups x 128
    const float *wp = A.projW + (size_t)(kc * 128) * 80 + col;
    const float *xk = s.out.xl + kc * 128;
    float a = 0.f;
#pragma unroll 4
    for (int kk = 0; kk < 128; ++kk) a += xk[kk] * wp[(size_t)kk * 80];
    s.out.part[kc * 81 + col] = a;
  } else if (tid < 972) {
    int kc = tid - 960;
    const float *xk = s.out.xl + kc * 128;
    const float *gk = A.gateW + kc * 128;
    float a = 0.f;
#pragma unroll 4
    for (int kk = 0; kk < 128; ++kk) a += xk[kk] * gk[kk];
    s.out.part[kc * 81 + 80] = a;
  }
  __syncthreads();
  if (tid < 81) {
    float sum = 0.f;
#pragma unroll
    for (int kc = 0; kc < 12; ++kc) sum += s.out.part[kc * 81 + tid];
    if (tid < 80) A.mel[((size_t)b * 80 + tid) * TDEC + tm] = sum + A.projB[tid];
    else          A.gate[(size_t)b * TDEC + tm] = sum + A.gateB[0];
  }
  __syncthreads();
}

// grid = 256 x 1024, 1 block/CU. LDS: w1h 65,536 + w2h 81,920 + Scr 14,080 = 161,536 B.
__global__ __launch_bounds__(NTHR) void k_persist(KArgs A) {
  __shared__ uint32_t w1h[128 * 128];   // z1 weight slice fp16 pairs [k2][col]
  __shared__ uint32_t w2h[160 * 128];   // z2 weight slice
  __shared__ Scr s;
  const int cb = blockIdx.x;
  const int tid = threadIdx.x;
  const int q = cb >> 5;                // z1: 0-6 (224 blk); z2: 0-7 (256 blk)
  const int c = cb & 31;

  // one-time weight staging (fp16 pairs)
  if (cb < 224) {
    for (int i = tid; i < 128 * 128; i += NTHR) {
      int k2 = i >> 7, col = i & 127, cg = c * 128 + col;
      int r0 = q * 256 + k2 * 2;        // boundary 768 even
      float f0 = (r0 < 768) ? A.aWih[(size_t)r0 * 4096 + cg]
                            : A.aWhh[(size_t)(r0 - 768) * 4096 + cg];
      float f1 = (r0 < 768) ? A.aWih[(size_t)(r0 + 1) * 4096 + cg]
                            : A.aWhh[(size_t)(r0 - 767) * 4096 + cg];
      w1h[i] = packh2(f0, f1);
    }
  }
  for (int i = tid; i < 160 * 128; i += NTHR) {
    int k2 = i >> 7, col = i & 127, cg = c * 128 + col;
    int r0 = q * 320 + k2 * 2;          // boundary 1536 even
    float f0 = (r0 < 1536) ? A.dWih[(size_t)r0 * 4096 + cg]
                           : A.dWhh[(size_t)(r0 - 1536) * 4096 + cg];
    float f1 = (r0 < 1536) ? A.dWih[(size_t)(r0 + 1) * 4096 + cg]
                           : A.dWhh[(size_t)(r0 - 1535) * 4096 + cg];
    w2h[i] = packh2(f0, f1);
  }
  __syncthreads();

  unsigned int ep = 0;
  for (int t = 0; t < TDEC; ++t) {
    const int p = t & 1;

    // ===== Seg A: Z1 (224 blk) || OUT(t-1) (16 blk) || prefetch pre(t+1) (2 blk) =====
    if (cb < 224) {
#pragma unroll
      for (int rep = 0; rep < 2; ++rep) {
        int i = tid + rep * 1024;       // 0-2047: pair-row k2 (0-127), batch b
        int k2 = i >> 4, b = i & 15;
        int lp = q * 128 + k2;          // logical pair-row 0-895
        int pp = (lp < 128) ? p * 128 + lp : 128 + lp;   // pre ping-pong remap
        s.z1s.xs1[i] = cload_u32(A.x1p + (size_t)pp * 16 + b);
      }
      __syncthreads();
      int col = tid & 127, bg = tid >> 7;
      float a0 = 0.f, a1 = 0.f;
      const uint32_t *wp = w1h + col;
      const uint32_t *xp = s.z1s.xs1 + bg * 2;
#pragma unroll 8
      for (int k2 = 0; k2 < 128; ++k2) {
        h2f16 w = u2h2(wp[k2 * 128]);
        a0 = fdot2(w, u2h2(xp[k2 * 16]), a0);
        a1 = fdot2(w, u2h2(xp[k2 * 16 + 1]), a1);
      }
      int cg = c * 128 + col;
      cstore(&A.z1[((size_t)q * 16 + bg * 2    ) * 4096 + cg], a0);
      cstore(&A.z1[((size_t)q * 16 + bg * 2 + 1) * 4096 + cg], a1);
    } else if (cb < 240) {
      if (t > 0) do_out(A, s, cb - 224, t - 1, tid);
    } else if (cb < 242) {
      if (t + 1 < TDEC) {
        int i = (cb - 240) * 1024 + tid;               // 0-2047
        cstore_u32(A.x1p + (size_t)(((t + 1) & 1) * 128) * 16 + i,
                   cload_u32(A.preTuP + (size_t)(t + 1) * 2048 + i));
      }
    }
    gsync(A.bar, ++ep, cb);

    // ===== Seg B: A-LSTM + pq partials (all 256: 16b x 16ug) =====
    {
      int b = cb & 15, ug = cb >> 4;
      {
        int u_l = tid & 63, j = tid >> 6;
        int kc = j & 7, gh = j >> 3;
        F2 pv; pv.x = 0.f; pv.y = 0.f;
        if (kc < 7) {
          const float *zb = A.z1 + ((size_t)(kc * 16 + b)) * 4096 + gh * 2048 + (ug * 64 + u_l);
          pv.x = cload(zb); pv.y = cload(zb + 1024);
        }
        s.al.part[j * 64 + u_l] = pv;
      }
      __syncthreads();
      if (tid < 64) {
        int uu = ug * 64 + tid;
        float g0 = 0.f, g1 = 0.f, g2 = 0.f, g3 = 0.f;
#pragma unroll
        for (int kc = 0; kc < 8; ++kc) {
          F2 v0 = s.al.part[kc * 64 + tid];
          F2 v1 = s.al.part[(8 + kc) * 64 + tid];
          g0 += v0.x; g1 += v0.y; g2 += v1.x; g3 += v1.y;
        }
        float zi = g0 + A.ab[uu], zf = g1 + A.ab[1024 + uu];
        float zg = g2 + A.ab[2048 + uu], zo = g3 + A.ab[3072 + uu];
        float cn = sigm(zf) * A.ac[b * 1024 + uu] + sigm(zi) * ftanh(zg);
        float hn = sigm(zo) * ftanh(cn);
        A.ac[b * 1024 + uu] = cn;
        s.al.hn[tid] = hn;
        float hn2 = __shfl_down(hn, 1);
        if (!(tid & 1)) {
          uint32_t pk = packh2(hn, hn2);
          int prw = uu >> 1;            // 0-511
          cstore_u32(A.x1p + (size_t)(512 + prw) * 16 + b, pk);
          cstore_u32(A.x2p + (size_t)prw * 16 + b, pk);
        }
      }
      __syncthreads();
      if (tid < 128) {
        float a = 0.f;
        const float *wq = A.Wq + (size_t)(ug * 64) * 128 + tid;
#pragma unroll 4
        for (int k = 0; k < 64; ++k) a += s.al.hn[k] * wq[(size_t)k * 128];
        cstore(&A.pqp[(size_t)(b * 16 + ug) * 128 + tid], a);
      }
    }
    gsync(A.bar, ++ep, cb);

    // ===== Seg C: ATT-A conv + energies (64 blk: 16b x 4 tt-slabs) =====
    if (cb < 64) {
      int b = cb & 15, tq = cb >> 4;
      if (tid < 96) {
        int gi = tq * 64 - 16 + tid;
        bool ok = (gi >= 0 && gi < 256);
        s.att.aw_l[tid]  = ok ? cload(&A.aw[b * 256 + gi])  : 0.f;
        s.att.awc_l[tid] = ok ? cload(&A.awc[b * 256 + gi]) : 0.f;
      }
      if (tid >= 128 && tid < 256) {
        int j = tid - 128;
        float sum = 0.f;
#pragma unroll
        for (int g = 0; g < 16; ++g) sum += cload(&A.pqp[(size_t)(b * 16 + g) * 128 + j]);
        s.att.pq[j] = sum;
      }
      __syncthreads();
      {
        int tt_l = tid & 63, fg = tid >> 6;
        int f0 = fg * 2;
        float a0 = 0.f, a1 = 0.f;
        for (int k = 0; k < KSIZE; ++k) {
          float av = s.att.aw_l[tt_l + k + 1];
          float cv = s.att.awc_l[tt_l + k + 1];
          a0 += av * A.convW[f0 * 62 + k]       + cv * A.convW[f0 * 62 + 31 + k];
          a1 += av * A.convW[(f0 + 1) * 62 + k] + cv * A.convW[(f0 + 1) * 62 + 31 + k];
        }
        s.att.lc[tt_l * 33 + f0]     = a0;
        s.att.lc[tt_l * 33 + f0 + 1] = a1;
      }
      __syncthreads();
      {
        int tt_l = tid & 63, g = tid >> 6;
        int tt = tq * 64 + tt_l, j0 = g * 8;
        float acc[8] = {0, 0, 0, 0, 0, 0, 0, 0};
        for (int f = 0; f < NFILT; ++f) {
          float lv = s.att.lc[tt_l * 33 + f];
          const float *lw = A.ldW + f * ATTN + j0;
#pragma unroll
          for (int jj = 0; jj < 8; ++jj) acc[jj] += lv * lw[jj];
        }
        float es = 0.f;
#pragma unroll
        for (int jj = 0; jj < 8; ++jj) {
          float sv = acc[jj] + s.att.pq[j0 + jj]
                   + bf2f(A.pmu[((size_t)(b * 128 + j0 + jj)) * 256 + tt]);
          es += ftanh(sv) * A.vw[j0 + jj];
        }
        s.att.ep[tt_l * 17 + g] = es;
      }
      __syncthreads();
      if (tid < 64) {
        float e = 0.f;
#pragma unroll
        for (int g = 0; g < 16; ++g) e += s.att.ep[tid * 17 + g];
        int tt = tq * 64 + tid;
        if (tt >= A.mlen[b]) e = -1e9f;
        cstore(&A.ebuf[b * 256 + tt], e);
      }
    }
    gsync(A.bar, ++ep, cb);

    // ===== Seg D: softmax (replicated) + ctx (all 256: 16b x 16 e-chunks) =====
    {
      int b = cb & 15, ec = cb >> 4;
      if (tid < 256) s.ctc.e_l[tid] = cload(&A.ebuf[b * 256 + tid]);
      __syncthreads();
      if (tid < 32) {
        float m = -1e30f;
#pragma unroll
        for (int i = 0; i < 8; ++i) m = fmaxf(m, s.ctc.e_l[tid * 8 + i]);
        s.ctc.red[tid] = m;
      }
      __syncthreads();
      if (tid == 0) {
        float m = -1e30f;
        for (int i = 0; i < 32; ++i) m = fmaxf(m, s.ctc.red[i]);
        s.ctc.smax = m;
      }
      __syncthreads();
      if (tid < 256) s.ctc.e_l[tid] = __expf(s.ctc.e_l[tid] - s.ctc.smax);
      __syncthreads();
      if (tid < 32) {
        float sm = 0.f;
#pragma unroll
        for (int i = 0; i < 8; ++i) sm += s.ctc.e_l[tid * 8 + i];
        s.ctc.red[tid] = sm;
      }
      __syncthreads();
      if (tid == 0) {
        float sm = 0.f;
        for (int i = 0; i < 32; ++i) sm += s.ctc.red[i];
        s.ctc.sinv = 1.f / sm;
      }
      __syncthreads();
      if (tid < 256) s.ctc.e_l[tid] *= s.ctc.sinv;
      __syncthreads();
      if (ec == 0 && tid < 256) {
        float w = s.ctc.e_l[tid];
        cstore(&A.aw[b * 256 + tid], w);
        cstore(&A.awc[b * 256 + tid], cload(&A.awc[b * 256 + tid]) + w);
        A.algn[((size_t)b * TDEC + t) * TENC + tid] = w;
      }
      {
        int e_l = tid & 31, sub = tid >> 5;
        const float *mp = A.memory + ((size_t)(b * 256) + sub * 8) * 512 + ec * 32 + e_l;
        float a = 0.f;
#pragma unroll
        for (int i = 0; i < 8; ++i) a += s.ctc.e_l[sub * 8 + i] * mp[(size_t)i * 512];
        s.ctc.part[e_l * 33 + sub] = a;
      }
      __syncthreads();
      if (tid < 32) {
        float sum = 0.f;
#pragma unroll
        for (int i = 0; i < 32; ++i) sum += s.ctc.part[tid * 33 + i];
        int eg = ec * 32 + tid;
        cstore(&A.ctxf[(size_t)eg * 16 + b], sum);
        float s2 = __shfl_down(sum, 1);
        if (!(tid & 1)) {
          uint32_t pk = packh2(sum, s2);
          int prw = eg >> 1;            // 0-255
          cstore_u32(A.x1p + (size_t)(256 + prw) * 16 + b, pk);
          cstore_u32(A.x2p + (size_t)(512 + prw) * 16 + b, pk);
        }
      }
    }
    gsync(A.bar, ++ep, cb);

    // ===== Seg E: Z2 (all 256: 8q x 32c, 160 pair-rows) =====
    {
      for (int i = tid; i < 160 * 16; i += NTHR) {
        int k2 = i >> 4, b = i & 15;
        s.z2s.xs2[i] = cload_u32(A.x2p + (size_t)(q * 160 + k2) * 16 + b);
      }
      __syncthreads();
      int col = tid & 127, bg = tid >> 7;
      float a0 = 0.f, a1 = 0.f;
      const uint32_t *wp = w2h + col;
      const uint32_t *xp = s.z2s.xs2 + bg * 2;
#pragma unroll 8
      for (int k2 = 0; k2 < 160; ++k2) {
        h2f16 w = u2h2(wp[k2 * 128]);
        a0 = fdot2(w, u2h2(xp[k2 * 16]), a0);
        a1 = fdot2(w, u2h2(xp[k2 * 16 + 1]), a1);
      }
      int cg = c * 128 + col;
      cstore(&A.z2[((size_t)q * 16 + bg * 2    ) * 4096 + cg], a0);
      cstore(&A.z2[((size_t)q * 16 + bg * 2 + 1) * 4096 + cg], a1);
    }
    gsync(A.bar, ++ep, cb);
  }

  // tail: OUT for t = TDEC-1
  if (cb >= 224 && cb < 240) do_out(A, s, cb - 224, TDEC - 1, tid);
}

extern "C" void kernel_launch(void *const *d_in, const int *in_sizes, int n_in,
                              void *d_out, int out_size, void *d_ws, size_t ws_size,
                              hipStream_t stream) {
  (void)in_sizes; (void)n_in; (void)out_size; (void)ws_size;
  const float *memory = (const float *)d_in[0];
  const float *dec_in = (const float *)d_in[1];
  const int   *mlen   = (const int *)d_in[2];
  const float *pw1    = (const float *)d_in[3];
  const float *pw2    = (const float *)d_in[4];
  const float *aWih   = (const float *)d_in[5];
  const float *aWhh   = (const float *)d_in[6];
  const float *ab     = (const float *)d_in[7];
  const float *wq     = (const float *)d_in[8];
  const float *wmem   = (const float *)d_in[9];
  const float *vw     = (const float *)d_in[10];
  const float *convW  = (const float *)d_in[11];
  const float *ldW    = (const float *)d_in[12];
  const float *dWih   = (const float *)d_in[13];
  const float *dWhh   = (const float *)d_in[14];
  const float *db     = (const float *)d_in[15];
  const float *projW  = (const float *)d_in[16];
  const float *projB  = (const float *)d_in[17];
  const float *gateW  = (const float *)d_in[18];
  const float *gateB  = (const float *)d_in[19];

  float *out_mel  = (float *)d_out;
  float *out_gate = out_mel + (size_t)16 * 80 * 200;
  float *out_algn = out_gate + (size_t)16 * 200;

  float *ws = (float *)d_ws;
  float *aw    = ws + OFF_AW;
  float *awc   = ws + OFF_AWC;
  float *ac    = ws + OFF_AC;
  float *dc    = ws + OFF_DC;
  uint32_t *x1p = (uint32_t *)(ws + OFF_X1P);
  uint32_t *x2p = (uint32_t *)(ws + OFF_X2P);
  float *ctxf  = ws + OFF_CTXF;
  uint32_t *preTuP = (uint32_t *)(ws + OFF_PRETU);
  u16 *pmu   = (u16 *)(ws + OFF_PMU);
  float *z1   = ws + OFF_Z1;
  float *z2   = ws + OFF_Z2;
  float *pqp  = ws + OFF_PQP;
  float *ebuf = ws + OFF_EBUF;
  unsigned int *bar = (unsigned int *)(ws + OFF_BAR);
  u16 *x1u   = (u16 *)z1;                  // prenet temp alias (pre-loop only)

  hipMemsetAsync(ws, 0, STATE_F * sizeof(float), stream);
  hipMemsetAsync(bar, 0, 2048 * sizeof(unsigned int), stream);

  uint32_t K1a, K1b, K2a, K2b;
  tf2x32(0u, 42u, 0u, 0u, K1a, K1b);
  tf2x32(0u, 42u, 0u, 1u, K2a, K2b);

  k_prenet1<<<TDEC * BB, 256, 0, stream>>>(dec_in, pw1, x1u, K1a, K1b);
  k_prenet2<<<TDEC * BB, 256, 0, stream>>>(x1u, pw2, preTuP, x1p, K2a, K2b);
  k_pm<<<64, 256, 0, stream>>>(memory, wmem, pmu);

  KArgs ka;
  ka.memory = memory; ka.mlen = mlen;
  ka.aWih = aWih; ka.aWhh = aWhh; ka.ab = ab;
  ka.Wq = wq; ka.vw = vw; ka.convW = convW; ka.ldW = ldW;
  ka.dWih = dWih; ka.dWhh = dWhh; ka.db = db;
  ka.projW = projW; ka.projB = projB; ka.gateW = gateW; ka.gateB = gateB;
  ka.preTuP = preTuP; ka.pmu = pmu;
  ka.x1p = x1p; ka.x2p = x2p;
  ka.aw = aw; ka.awc = awc; ka.ac = ac; ka.dc = dc; ka.ctxf = ctxf;
  ka.z1 = z1; ka.z2 = z2; ka.pqp = pqp; ka.ebuf = ebuf;
  ka.bar = bar;
  ka.mel = out_mel; ka.gate = out_gate; ka.algn = out_algn;

  void *kp[] = { &ka };
  hipLaunchCooperativeKernel((void *)k_persist, dim3(NBLK), dim3(NTHR), kp, 0, stream);
}